// Round 4
// baseline (225.936 us; speedup 1.0000x reference)
//
#include <hip/hip_runtime.h>
#include <math.h>

#define B_  8
#define S_  512
#define D_  512
#define H_  8
#define DK_ 64
#define KL_ 1024

typedef __attribute__((ext_vector_type(8))) short bf16x8;
typedef __attribute__((ext_vector_type(4))) float f32x4;

__device__ __forceinline__ unsigned short f2bf(float f) {   // RNE
    unsigned u = __float_as_uint(f);
    u += 0x7FFF + ((u >> 16) & 1);
    return (unsigned short)(u >> 16);
}
// pack two fp32 -> (bf16(hi)<<16)|bf16(lo), TRUNCATED (1 v_perm)
__device__ __forceinline__ unsigned pkbf(float lo, float hi) {
    return __builtin_amdgcn_perm(__float_as_uint(hi), __float_as_uint(lo), 0x07060302u);
}
__device__ __forceinline__ bf16x8 pack8(float4 a, float4 b) {
    union { bf16x8 v; unsigned u[4]; } r;
    r.u[0] = pkbf(a.x, a.y); r.u[1] = pkbf(a.z, a.w);
    r.u[2] = pkbf(b.x, b.y); r.u[3] = pkbf(b.z, b.w);
    return r.v;
}

// async global->LDS, 16 B per lane; LDS dest = wave-uniform base + lane*16
__device__ __forceinline__ void gld16(const void* g, void* l) {
    __builtin_amdgcn_global_load_lds(
        (const __attribute__((address_space(1))) unsigned int*)g,
        (__attribute__((address_space(3))) unsigned int*)l, 16, 0, 0);
}

// ---------------------------------------------------------------------------
// prep: [blocks 0..1407]   convert x,Wq,Wk,Wv fp32->bf16 (+offset scalar)
//       [blocks 1408..3455] cache shift prev rows 512..1023 -> fp32 rows 0..511
// ---------------------------------------------------------------------------
__global__ __launch_bounds__(256)
void prep_kernel(const float* __restrict__ x,  const float* __restrict__ Wq,
                 const float* __restrict__ Wk, const float* __restrict__ Wv,
                 const float4* __restrict__ pk, const float4* __restrict__ pv,
                 unsigned short* __restrict__ xb,  unsigned short* __restrict__ Wqb,
                 unsigned short* __restrict__ Wkb, unsigned short* __restrict__ Wvb,
                 float4* __restrict__ kout4, float4* __restrict__ vout4,
                 float* __restrict__ off_out) {
    const int blk = blockIdx.x, t = threadIdx.x;
    if (blk < 1408) {
        int i = blk * 256 + t;                  // 0 .. 360447
        if (i == 0) off_out[0] = 1024.0f;
        const float* src; unsigned short* dst; int off;
        if (i < 262144)      { src = x;  dst = xb;  off = i; }
        else if (i < 294912) { src = Wq; dst = Wqb; off = i - 262144; }
        else if (i < 327680) { src = Wk; dst = Wkb; off = i - 294912; }
        else                 { src = Wv; dst = Wvb; off = i - 327680; }
        float4 v0 = ((const float4*)src)[off * 2];
        float4 v1 = ((const float4*)src)[off * 2 + 1];
        unsigned short tmp[8] = {f2bf(v0.x), f2bf(v0.y), f2bf(v0.z), f2bf(v0.w),
                                 f2bf(v1.x), f2bf(v1.y), f2bf(v1.z), f2bf(v1.w)};
        *(uint4*)&dst[off * 8] = *(uint4*)tmp;
    } else {
        int i = (blk - 1408) * 256 + t;         // 0 .. 524287
        int bh = i >> 13, r4 = i & 8191;
        kout4[bh * 16384 + r4] = pk[bh * 16384 + 8192 + r4];
        vout4[bh * 16384 + r4] = pv[bh * 16384 + 8192 + r4];
    }
}

// ---------------------------------------------------------------------------
// MFMA GEMM, 128x64 tile, 4 waves 2x2 (wave tile 64x32), BK=32.
// C(4096x512) = A_bf16 @ W^T + bias.
// MODE 1: A=xb row-major; C bf16 *0.125 scatter (B,H,S,DK)       [Q]
// MODE 2: A=xb row-major; C fp32 scatter (B,H,KL,DK) rows 512+   [K/V]
// MODE 3: A=Ob in (B,H,S,DK) layout; W fp32 (trunc-convert); C fp32 row-major
// ---------------------------------------------------------------------------
template<int MODE>
__device__ __forceinline__
void mfma_gemm_body(const unsigned short* __restrict__ A,
                    const unsigned short* __restrict__ Wb,
                    const float* __restrict__ Wf,
                    const float* __restrict__ bias,
                    float* __restrict__ C32, unsigned short* __restrict__ C16) {
    __shared__ unsigned short As[128 * 32];
    __shared__ unsigned short Bs[64 * 32];
    const int t = threadIdx.x, l = t & 63, w = t >> 6;
    const int m16 = l & 15, quad = l >> 4;
    const int wm = w >> 1, wn = w & 1;
    const int bn = blockIdx.x, bm = blockIdx.y;
    const int lr = l >> 2, lc = (l & 3) * 8;    // 4 lanes per 64B row-piece

    f32x4 acc[4][2] = {};

    for (int k0 = 0; k0 < 512; k0 += 32) {
        __syncthreads();
        // ---- A staging: 8 chunks of 16 rows, waves take w*2, w*2+1 ----
        if (MODE == 3) {
            int h = k0 >> 6, dd0 = k0 & 63;
            const unsigned short* Ab = A + ((((bm >> 2) * 8 + h) * 512) + (bm & 3) * 128) * 64 + dd0;
            #pragma unroll
            for (int q = 0; q < 2; ++q) {
                int chunk = w * 2 + q;
                gld16(Ab + (chunk * 16 + lr) * 64 + lc, &As[chunk * 512 + l * 8]);
            }
        } else {
            const unsigned short* Ab = A + (bm * 128) * 512 + k0;
            #pragma unroll
            for (int q = 0; q < 2; ++q) {
                int chunk = w * 2 + q;
                gld16(Ab + (chunk * 16 + lr) * 512 + lc, &As[chunk * 512 + l * 8]);
            }
        }
        // ---- B staging: 4 chunks of 16 rows, wave w takes chunk w ----
        if (MODE == 3) {
            const float* Wg = Wf + ((bn * 64 + w * 16 + lr) * 512) + k0 + lc;
            float4 v0 = *(const float4*)Wg;
            float4 v1 = *(const float4*)(Wg + 4);
            *(bf16x8*)&Bs[w * 512 + l * 8] = pack8(v0, v1);
        } else {
            gld16(Wb + (bn * 64 + w * 16 + lr) * 512 + k0 + lc, &Bs[w * 512 + l * 8]);
        }
        __syncthreads();

        bf16x8 af[4], bfr[2];
        #pragma unroll
        for (int mm = 0; mm < 4; ++mm)
            af[mm] = *(const bf16x8*)&As[(wm * 64 + mm * 16 + m16) * 32 + quad * 8];
        #pragma unroll
        for (int nn = 0; nn < 2; ++nn)
            bfr[nn] = *(const bf16x8*)&Bs[(wn * 32 + nn * 16 + m16) * 32 + quad * 8];
        #pragma unroll
        for (int mm = 0; mm < 4; ++mm)
            #pragma unroll
            for (int nn = 0; nn < 2; ++nn)
                acc[mm][nn] = __builtin_amdgcn_mfma_f32_16x16x32_bf16(
                    af[mm], bfr[nn], acc[mm][nn], 0, 0, 0);
    }

    // epilogue: C/D row = quad*4+r, col = m16 [m89/m91]
    #pragma unroll
    for (int mm = 0; mm < 4; ++mm) {
        #pragma unroll
        for (int nn = 0; nn < 2; ++nn) {
            int n = bn * 64 + wn * 32 + nn * 16 + m16;
            float bv_ = bias[n];
            #pragma unroll
            for (int r = 0; r < 4; ++r) {
                int m = bm * 128 + wm * 64 + mm * 16 + quad * 4 + r;
                float val = acc[mm][nn][r] + bv_;
                if (MODE == 3) {
                    C32[m * 512 + n] = val;
                } else {
                    int b = m >> 9, s = m & 511;
                    int h = n >> 6, d = n & 63;
                    if (MODE == 1) C16[((b * H_ + h) * S_ + s) * DK_ + d] = f2bf(val * 0.125f);
                    else           C32[((b * H_ + h) * KL_ + 512 + s) * DK_ + d] = val;
                }
            }
        }
    }
}

__global__ __launch_bounds__(256)
void qkv_mfma_kernel(const unsigned short* __restrict__ xb,
                     const unsigned short* __restrict__ Wqb, const float* __restrict__ bq,
                     const unsigned short* __restrict__ Wkb, const float* __restrict__ bk,
                     const unsigned short* __restrict__ Wvb, const float* __restrict__ bv,
                     unsigned short* __restrict__ Qb, float* __restrict__ kout,
                     float* __restrict__ vout) {
    if (blockIdx.z == 0)      mfma_gemm_body<1>(xb, Wqb, nullptr, bq, nullptr, Qb);
    else if (blockIdx.z == 1) mfma_gemm_body<2>(xb, Wkb, nullptr, bk, kout, nullptr);
    else                      mfma_gemm_body<2>(xb, Wvb, nullptr, bv, vout, nullptr);
}

__global__ __launch_bounds__(256)
void out_mfma_kernel(const unsigned short* __restrict__ Ob, const float* __restrict__ Wo,
                     const float* __restrict__ bo, float* __restrict__ C) {
    mfma_gemm_body<3>(Ob, nullptr, Wo, bo, C, nullptr);
}

// ---------------------------------------------------------------------------
// V^T bf16 mirror: Vt[bh][d][key] <- vout[bh][key][d].  Grid (16 key-tiles, 64 bh).
// ---------------------------------------------------------------------------
__global__ __launch_bounds__(256)
void vt_kernel(const float* __restrict__ vout, unsigned short* __restrict__ Vt) {
    __shared__ float Ls[64][68];
    const int kt = blockIdx.x, bh = blockIdx.y;
    const int t = threadIdx.x;
    const float* Vg = vout + (bh * KL_ + (kt << 6)) * DK_;
    #pragma unroll
    for (int it = 0; it < 4; ++it) {
        int idx = t + (it << 8);
        int row = idx >> 4, c4 = idx & 15;
        *(float4*)&Ls[row][c4 << 2] = *(const float4*)&Vg[row * 64 + (c4 << 2)];
    }
    __syncthreads();
    int d = t >> 2, kp = (t & 3) << 4;          // 16 keys per thread
    unsigned short tmp[16];
    #pragma unroll
    for (int j = 0; j < 16; ++j) tmp[j] = f2bf(Ls[kp + j][d]);
    unsigned short* dst = Vt + (bh * DK_ + d) * KL_ + (kt << 6) + kp;
    *(uint4*)dst       = *(uint4*)tmp;
    *(uint4*)(dst + 8) = *(uint4*)(tmp + 8);
}

// ---------------------------------------------------------------------------
// Barrier-free MFMA flash attention. Block (bh, qt4) = 4 waves; each wave owns
// 16 queries (q0 = (qt4*4+w)*16) for head bh, end-to-end. K fragments read
// direct from global fp32 (v_perm truncate to bf16); V^T fragments direct from
// bf16 Vt. Only P round-trips through per-wave LDS. NO __syncthreads.
// O overwrites the Q buffer in place: wave reads rows (bh,q0..q0+15) at start,
// writes exactly those rows at the end — no cross-wave aliasing.
// ---------------------------------------------------------------------------
__global__ __launch_bounds__(256)
void attn_kernel(unsigned short* qo, const float* __restrict__ K,
                 const unsigned short* __restrict__ Vt) {
    const int bh = blockIdx.x, qt4 = blockIdx.y;
    const int t = threadIdx.x, l = t & 63, w = t >> 6;
    const int m16 = l & 15, quad = l >> 4;
    const int q0 = (qt4 * 4 + w) * 16;

    __shared__ __attribute__((aligned(16))) unsigned short Ps[4][16][72];

    bf16x8 qf[2];
    {
        const unsigned short* qrow = qo + (bh * S_ + q0 + m16) * DK_;
        qf[0] = *(const bf16x8*)(qrow + quad * 8);
        qf[1] = *(const bf16x8*)(qrow + 32 + quad * 8);
    }

    f32x4 acc[4];
    float m_run[4], l_run[4];
    #pragma unroll
    for (int r = 0; r < 4; ++r) {
        m_run[r] = -INFINITY; l_run[r] = 0.f;
        acc[r][0] = acc[r][1] = acc[r][2] = acc[r][3] = 0.f;
    }

    const int ktmax = (527 + q0) >> 6;           // one partial tile only (q0 % 16 == 0)
    const float* Kbh = K + (bh * KL_) * DK_;
    const unsigned short* Vbh = Vt + (bh * DK_) * KL_;

    for (int kt = 0; kt <= ktmax; ++kt) {
        // ---- S = Q K^T : K B-frags direct from global, truncate-convert ----
        const float* Kt = Kbh + (kt << 6) * DK_;
        f32x4 sacc[4];
        #pragma unroll
        for (int nn = 0; nn < 4; ++nn) {
            const float* kp = Kt + ((nn << 4) + m16) * DK_ + quad * 8;
            float4 a0 = *(const float4*)kp;
            float4 b0 = *(const float4*)(kp + 4);
            float4 a1 = *(const float4*)(kp + 32);
            float4 b1 = *(const float4*)(kp + 36);
            sacc[nn][0] = sacc[nn][1] = sacc[nn][2] = sacc[nn][3] = 0.f;
            sacc[nn] = __builtin_amdgcn_mfma_f32_16x16x32_bf16(qf[0], pack8(a0, b0), sacc[nn], 0, 0, 0);
            sacc[nn] = __builtin_amdgcn_mfma_f32_16x16x32_bf16(qf[1], pack8(a1, b1), sacc[nn], 0, 0, 0);
        }

        if (kt == ktmax) {                       // per-row causal mask, boundary tile only
            #pragma unroll
            for (int nn = 0; nn < 4; ++nn) {
                int key = (kt << 6) + (nn << 4) + m16;
                #pragma unroll
                for (int r = 0; r < 4; ++r)
                    if (key > 512 + q0 + (quad << 2) + r) sacc[nn][r] = -INFINITY;
            }
        }

        // ---- online softmax: row = quad*4+r, reduce over the quad's 16 lanes ----
        float mnew[4], alpha[4];
        #pragma unroll
        for (int r = 0; r < 4; ++r) {
            float mx = fmaxf(fmaxf(sacc[0][r], sacc[1][r]), fmaxf(sacc[2][r], sacc[3][r]));
            mx = fmaxf(mx, __shfl_xor(mx, 1));
            mx = fmaxf(mx, __shfl_xor(mx, 2));
            mx = fmaxf(mx, __shfl_xor(mx, 4));
            mx = fmaxf(mx, __shfl_xor(mx, 8));
            mnew[r]  = fmaxf(m_run[r], mx);
            alpha[r] = __expf(m_run[r] - mnew[r]);   // first tile: exp(-inf)=0
            m_run[r] = mnew[r];
        }
        #pragma unroll
        for (int r = 0; r < 4; ++r) {
            float ps = 0.f;
            #pragma unroll
            for (int nn = 0; nn < 4; ++nn) {
                float p = __expf(sacc[nn][r] - mnew[r]);
                ps += p;
                Ps[w][(quad << 2) + r][(nn << 4) + m16] = f2bf(p);
            }
            ps += __shfl_xor(ps, 1);
            ps += __shfl_xor(ps, 2);
            ps += __shfl_xor(ps, 4);
            ps += __shfl_xor(ps, 8);
            l_run[r] = l_run[r] * alpha[r] + ps;
        }
        #pragma unroll
        for (int nn = 0; nn < 4; ++nn)
            #pragma unroll
            for (int r = 0; r < 4; ++r) acc[nn][r] *= alpha[r];

        // ---- O += P V : P via per-wave LDS (in-order within wave), V^T direct ----
        bf16x8 pf0 = *(const bf16x8*)&Ps[w][m16][quad * 8];
        bf16x8 pf1 = *(const bf16x8*)&Ps[w][m16][32 + quad * 8];
        #pragma unroll
        for (int nn = 0; nn < 4; ++nn) {
            const unsigned short* vp = Vbh + ((nn << 4) + m16) * KL_ + (kt << 6) + quad * 8;
            bf16x8 vf0 = *(const bf16x8*)vp;
            bf16x8 vf1 = *(const bf16x8*)(vp + 32);
            acc[nn] = __builtin_amdgcn_mfma_f32_16x16x32_bf16(pf0, vf0, acc[nn], 0, 0, 0);
            acc[nn] = __builtin_amdgcn_mfma_f32_16x16x32_bf16(pf1, vf1, acc[nn], 0, 0, 0);
        }
    }

    // epilogue: overwrite qo rows (bh, q0..q0+15): row=quad*4+r, col=nn*16+m16
    unsigned short* Og = qo + (bh * S_ + q0) * DK_;
    #pragma unroll
    for (int r = 0; r < 4; ++r) {
        float inv = 1.f / l_run[r];
        #pragma unroll
        for (int nn = 0; nn < 4; ++nn)
            Og[((quad << 2) + r) * DK_ + (nn << 4) + m16] = f2bf(acc[nn][r] * inv);
    }
}

// ---------------------------------------------------------------------------
extern "C" void kernel_launch(void* const* d_in, const int* in_sizes, int n_in,
                              void* d_out, int out_size, void* d_ws, size_t ws_size,
                              hipStream_t stream) {
    const float* x  = (const float*)d_in[0];
    const float* pk = (const float*)d_in[1];
    const float* pv = (const float*)d_in[2];
    const float* Wq = (const float*)d_in[3];
    const float* bq = (const float*)d_in[4];
    const float* Wk = (const float*)d_in[5];
    const float* bk = (const float*)d_in[6];
    const float* Wv = (const float*)d_in[7];
    const float* bv = (const float*)d_in[8];
    const float* Wo = (const float*)d_in[9];
    const float* bo = (const float*)d_in[10];

    float* out     = (float*)d_out;            // (8,512,512)
    float* kout    = out + 2097152;            // (8,8,1024,64)
    float* vout    = kout + 4194304;           // (8,8,1024,64)
    float* off_out = vout + 4194304;           // scalar 1024.0

    // 16 MB workspace, lifetime-aliased:
    unsigned short* Qb  = (unsigned short*)d_ws;   // [0,4MB)  Q bf16 (B,H,S,DK); O in place after attn
    unsigned short* Vt  = Qb + 2097152;            // [4,12MB) V^T bf16 (B,H,DK,KL), live vt..attn
    unsigned short* xb  = Vt + 4194304;            // [12,16MB) x bf16, live prep..qkv
    unsigned short* Wqb = Vt;                      // W bf16 alias in Vt head: dead before vt_kernel
    unsigned short* Wkb = Wqb + 262144;
    unsigned short* Wvb = Wkb + 262144;

    // 1) convert + cache shift + offset (fused)
    prep_kernel<<<3456, 256, 0, stream>>>(x, Wq, Wk, Wv, (const float4*)pk, (const float4*)pv,
                                          xb, Wqb, Wkb, Wvb,
                                          (float4*)kout, (float4*)vout, off_out);
    // 2) QKV projections (128x64 tiles, 768 blocks)
    qkv_mfma_kernel<<<dim3(8, 32, 3), 256, 0, stream>>>(xb, Wqb, bq, Wkb, bk, Wvb, bv,
                                                        Qb, kout, vout);
    // 3) V^T mirror for PV fragment loads
    vt_kernel<<<dim3(16, 64), 256, 0, stream>>>(vout, Vt);
    // 4) barrier-free attention; O replaces Q in Qb
    attn_kernel<<<dim3(64, 8), 256, 0, stream>>>(Qb, kout, Vt);
    // 5) output projection (A = Qb in (B,H,S,DK) layout)
    out_mfma_kernel<<<dim3(8, 32), 256, 0, stream>>>(Qb, Wo, bo, out);
}

// Round 5
// 166.501 us; speedup vs baseline: 1.3570x; 1.3570x over previous
//
#include <hip/hip_runtime.h>
#include <math.h>

#define B_  8
#define S_  512
#define D_  512
#define H_  8
#define DK_ 64
#define KL_ 1024

typedef __attribute__((ext_vector_type(8))) short bf16x8;
typedef __attribute__((ext_vector_type(4))) float f32x4;

__device__ __forceinline__ unsigned short f2bf(float f) {   // RNE
    unsigned u = __float_as_uint(f);
    u += 0x7FFF + ((u >> 16) & 1);
    return (unsigned short)(u >> 16);
}
// pack two fp32 -> (bf16(hi)<<16)|bf16(lo), TRUNCATED (1 v_perm)
__device__ __forceinline__ unsigned pkbf(float lo, float hi) {
    return __builtin_amdgcn_perm(__float_as_uint(hi), __float_as_uint(lo), 0x07060302u);
}
__device__ __forceinline__ bf16x8 pack8(float4 a, float4 b) {
    union { bf16x8 v; unsigned u[4]; } r;
    r.u[0] = pkbf(a.x, a.y); r.u[1] = pkbf(a.z, a.w);
    r.u[2] = pkbf(b.x, b.y); r.u[3] = pkbf(b.z, b.w);
    return r.v;
}
// async global->LDS, 16 B per lane; LDS dest = wave-uniform base + lane*16
__device__ __forceinline__ void gld16(const void* g, void* l) {
    __builtin_amdgcn_global_load_lds(
        (const __attribute__((address_space(1))) unsigned int*)g,
        (__attribute__((address_space(3))) unsigned int*)l, 16, 0, 0);
}

// ---------------------------------------------------------------------------
// prep: cache shift prev rows 512..1023 -> fp32 rows 0..511 (+offset scalar)
// ---------------------------------------------------------------------------
__global__ __launch_bounds__(256)
void prep_kernel(const float4* __restrict__ pk, const float4* __restrict__ pv,
                 float4* __restrict__ kout4, float4* __restrict__ vout4,
                 float* __restrict__ off_out) {
    int i = blockIdx.x * 256 + threadIdx.x;     // 0 .. 524287
    int bh = i >> 13, r4 = i & 8191;
    kout4[bh * 16384 + r4] = pk[bh * 16384 + 8192 + r4];
    vout4[bh * 16384 + r4] = pv[bh * 16384 + 8192 + r4];
    if (i == 0) off_out[0] = 1024.0f;
}

// ---------------------------------------------------------------------------
// MFMA GEMM, BMx64 tile, 4 waves 2x2 (wave tile (BM/2)x32), BK=32.
// C(4096x512) = A @ W^T + bias.  W always fp32, converted in-kernel.
// MODE 1: A fp32 row-major; C bf16 *0.125 scatter (B,H,S,DK)      [Q]
// MODE 2: A fp32 row-major; C fp32 scatter (B,H,KL,DK) rows 512+  [K/V]
// MODE 3: A bf16 in (B,H,S,DK); C fp32 row-major                  [out]
// ---------------------------------------------------------------------------
template<int MODE, int BM>
__device__ __forceinline__
void mfma_gemm_body(const float* __restrict__ A32,
                    const unsigned short* __restrict__ A16,
                    const float* __restrict__ Wf,
                    const float* __restrict__ bias,
                    float* __restrict__ C32, unsigned short* __restrict__ C16) {
    constexpr int MM = BM / 32;                 // m-tiles per wave
    __shared__ unsigned short As[BM * 32];
    __shared__ unsigned short Bs[64 * 32];
    const int t = threadIdx.x, l = t & 63, w = t >> 6;
    const int m16 = l & 15, quad = l >> 4;
    const int wm = w >> 1, wn = w & 1;
    const int bn = blockIdx.x, bm = blockIdx.y;

    f32x4 acc[MM][2] = {};

    for (int k0 = 0; k0 < 512; k0 += 32) {
        __syncthreads();
        if (MODE == 3) {
            // A16 (B,H,S,DK): row m=b*512+s, col k=h*64+d.  BM=64 here.
            const int h = k0 >> 6, dd0 = k0 & 63;
            const int lr = l >> 2, lc = (l & 3) * 8;
            const unsigned short* Ab =
                A16 + (((bm >> 3) * 8 + h) * 512 + (bm & 7) * 64) * 64 + dd0;
            gld16(Ab + (w * 16 + lr) * 64 + lc, &As[w * 512 + l * 8]);
        } else {
            #pragma unroll
            for (int s = 0; s < BM / 64; ++s) {
                int id = t + s * 256;           // 0 .. BM*4-1
                int row = id >> 2, c8 = id & 3;
                const float* src = A32 + (bm * BM + row) * 512 + k0 + c8 * 8;
                float4 v0 = *(const float4*)src;
                float4 v1 = *(const float4*)(src + 4);
                *(bf16x8*)&As[row * 32 + c8 * 8] = pack8(v0, v1);
            }
        }
        {   // B: 64x32 fp32 -> bf16
            int row = t >> 2, c8 = t & 3;
            const float* src = Wf + (bn * 64 + row) * 512 + k0 + c8 * 8;
            float4 v0 = *(const float4*)src;
            float4 v1 = *(const float4*)(src + 4);
            *(bf16x8*)&Bs[row * 32 + c8 * 8] = pack8(v0, v1);
        }
        __syncthreads();

        bf16x8 af[MM], bfr[2];
        #pragma unroll
        for (int mm = 0; mm < MM; ++mm)
            af[mm] = *(const bf16x8*)&As[(wm * (BM / 2) + mm * 16 + m16) * 32 + quad * 8];
        #pragma unroll
        for (int nn = 0; nn < 2; ++nn)
            bfr[nn] = *(const bf16x8*)&Bs[(wn * 32 + nn * 16 + m16) * 32 + quad * 8];
        #pragma unroll
        for (int mm = 0; mm < MM; ++mm)
            #pragma unroll
            for (int nn = 0; nn < 2; ++nn)
                acc[mm][nn] = __builtin_amdgcn_mfma_f32_16x16x32_bf16(
                    af[mm], bfr[nn], acc[mm][nn], 0, 0, 0);
    }

    // epilogue: C/D row = quad*4+r, col = m16 [m89/m91]
    #pragma unroll
    for (int mm = 0; mm < MM; ++mm) {
        #pragma unroll
        for (int nn = 0; nn < 2; ++nn) {
            int n = bn * 64 + wn * 32 + nn * 16 + m16;
            float bv_ = bias[n];
            #pragma unroll
            for (int r = 0; r < 4; ++r) {
                int m = bm * BM + wm * (BM / 2) + mm * 16 + quad * 4 + r;
                float val = acc[mm][nn][r] + bv_;
                if (MODE == 3) {
                    C32[m * 512 + n] = val;
                } else {
                    int b = m >> 9, s = m & 511;
                    int h = n >> 6, d = n & 63;
                    if (MODE == 1) C16[((b * H_ + h) * S_ + s) * DK_ + d] = f2bf(val * 0.125f);
                    else           C32[((b * H_ + h) * KL_ + 512 + s) * DK_ + d] = val;
                }
            }
        }
    }
}

__global__ __launch_bounds__(256)
void qkv_mfma_kernel(const float* __restrict__ x,
                     const float* __restrict__ Wq, const float* __restrict__ bq,
                     const float* __restrict__ Wk, const float* __restrict__ bk,
                     const float* __restrict__ Wv, const float* __restrict__ bv,
                     unsigned short* __restrict__ Qb, float* __restrict__ kout,
                     float* __restrict__ vout) {
    if (blockIdx.z == 0)      mfma_gemm_body<1, 128>(x, nullptr, Wq, bq, nullptr, Qb);
    else if (blockIdx.z == 1) mfma_gemm_body<2, 128>(x, nullptr, Wk, bk, kout, nullptr);
    else                      mfma_gemm_body<2, 128>(x, nullptr, Wv, bv, vout, nullptr);
}

__global__ __launch_bounds__(256)
void out_mfma_kernel(const unsigned short* __restrict__ Ob, const float* __restrict__ Wo,
                     const float* __restrict__ bo, float* __restrict__ C) {
    mfma_gemm_body<3, 64>(nullptr, Ob, Wo, bo, C, nullptr);
}

// ---------------------------------------------------------------------------
// Pack K and V into MFMA B-fragment linear order (bf16):
//  Kp[(bh*16+kt)*4096 + c*512 + l*8 + j] = K[bh][kt*64 + (c>>1)*16 + (l&15)]
//                                           [(c&1)*32 + (l>>4)*8 + j]
//  Vp[...same idx...]                   = V[bh][kt*64 + (c&1)*32 + (l>>4)*8 + j]
//                                           [(c>>1)*16 + (l&15)]
// A wave then reads one chunk with `base + lane*16` -> fully coalesced 1 KB.
// ---------------------------------------------------------------------------
__global__ __launch_bounds__(256)
void pack_kernel(const float* __restrict__ kout, const float* __restrict__ vout,
                 unsigned short* __restrict__ Kp, unsigned short* __restrict__ Vp) {
    __shared__ float Kl[64][68];
    __shared__ float Vl[64][68];
    const int kt = blockIdx.x, bh = blockIdx.y;
    const int t = threadIdx.x;
    const float* Kg = kout + (bh * KL_ + kt * 64) * DK_;
    const float* Vg = vout + (bh * KL_ + kt * 64) * DK_;
    #pragma unroll
    for (int it = 0; it < 4; ++it) {
        int idx = t + it * 256;                 // 1024 float4 slots
        int row = idx >> 4, c4 = idx & 15;
        *(float4*)&Kl[row][c4 * 4] = *(const float4*)&Kg[row * 64 + c4 * 4];
        *(float4*)&Vl[row][c4 * 4] = *(const float4*)&Vg[row * 64 + c4 * 4];
    }
    __syncthreads();
    unsigned short* Kpb = Kp + (bh * 16 + kt) * 4096;
    unsigned short* Vpb = Vp + (bh * 16 + kt) * 4096;
    #pragma unroll
    for (int s = 0; s < 2; ++s) {
        int slot = t + s * 256;                 // 0..511
        int c = slot >> 6, l = slot & 63;
        int nn = c >> 1, hf = c & 1;
        {   // K chunk: rows nn*16+(l&15), cols hf*32+(l>>4)*8 ..+7
            int row = nn * 16 + (l & 15), col = hf * 32 + (l >> 4) * 8;
            unsigned short tmp[8];
            #pragma unroll
            for (int j = 0; j < 8; ++j) tmp[j] = f2bf(Kl[row][col + j]);
            *(uint4*)&Kpb[c * 512 + l * 8] = *(uint4*)tmp;
        }
        {   // V chunk: rows hf*32+(l>>4)*8+j, col nn*16+(l&15)
            int row0 = hf * 32 + (l >> 4) * 8, col = nn * 16 + (l & 15);
            unsigned short tmp[8];
            #pragma unroll
            for (int j = 0; j < 8; ++j) tmp[j] = f2bf(Vl[row0 + j][col]);
            *(uint4*)&Vpb[c * 512 + l * 8] = *(uint4*)tmp;
        }
    }
}

// ---------------------------------------------------------------------------
// Packed-fragment flash attention, no-max softmax, split-K across 2 waves.
// Block (bh, qg): 128 thr = 2 waves sharing 32 queries q0=qg*32; wave w takes
// key-tiles kt = w, w+2, ...  All K/V fragment loads are coalesced 16B/lane
// from Kp/Vp. No barriers in the loop; ONE barrier to combine partials
// (valid because p=exp(s) with no running max => partials add linearly).
// O overwrites Q rows in place (wave-exclusive rows).
// ---------------------------------------------------------------------------
__global__ __launch_bounds__(128)
void attn_kernel(unsigned short* qo, const unsigned short* __restrict__ Kp,
                 const unsigned short* __restrict__ Vp) {
    const int bh = blockIdx.x, qg = blockIdx.y;
    const int t = threadIdx.x, l = t & 63, w = t >> 6;
    const int m16 = l & 15, quad = l >> 4;
    const int q0 = qg * 32;

    __shared__ __attribute__((aligned(16))) unsigned short Ps[2][32][72];
    __shared__ float comb[64][40];

    bf16x8 qf[2][2];
    #pragma unroll
    for (int h = 0; h < 2; ++h)
        #pragma unroll
        for (int p = 0; p < 2; ++p)
            qf[h][p] = *(const bf16x8*)(qo + (bh * S_ + q0 + h * 16 + m16) * DK_
                                           + p * 32 + quad * 8);

    f32x4 acc[2][4] = {};
    float psum[2][4] = {};

    const int ktmax = (543 + q0) >> 6;          // last (only) partially-masked tile
    const unsigned short* Kpb = Kp + (bh * 16) * 4096;
    const unsigned short* Vpb = Vp + (bh * 16) * 4096;

    for (int kt = w; kt <= ktmax; kt += 2) {
        const unsigned short* kb = Kpb + kt * 4096;
        const unsigned short* vb = Vpb + kt * 4096;
        bf16x8 kf[4][2], vf[4][2];
        #pragma unroll
        for (int nn = 0; nn < 4; ++nn)
            #pragma unroll
            for (int hf = 0; hf < 2; ++hf) {
                kf[nn][hf] = *(const bf16x8*)(kb + ((nn * 2 + hf) * 64 + l) * 8);
                vf[nn][hf] = *(const bf16x8*)(vb + ((nn * 2 + hf) * 64 + l) * 8);
            }

        // S = Q K^T (scale pre-folded into Q)
        f32x4 sc[2][4];
        #pragma unroll
        for (int h = 0; h < 2; ++h)
            #pragma unroll
            for (int nn = 0; nn < 4; ++nn) {
                sc[h][nn][0] = sc[h][nn][1] = sc[h][nn][2] = sc[h][nn][3] = 0.f;
                sc[h][nn] = __builtin_amdgcn_mfma_f32_16x16x32_bf16(qf[h][0], kf[nn][0], sc[h][nn], 0, 0, 0);
                sc[h][nn] = __builtin_amdgcn_mfma_f32_16x16x32_bf16(qf[h][1], kf[nn][1], sc[h][nn], 0, 0, 0);
            }

        if (kt == ktmax) {                      // causal mask, boundary tile only
            #pragma unroll
            for (int h = 0; h < 2; ++h)
                #pragma unroll
                for (int nn = 0; nn < 4; ++nn) {
                    int key = kt * 64 + nn * 16 + m16;
                    #pragma unroll
                    for (int r = 0; r < 4; ++r)
                        if (key > 512 + q0 + h * 16 + (quad << 2) + r)
                            sc[h][nn][r] = -INFINITY;
                }
        }

        // p = exp(s); accumulate row partial sums; store P in A-frag layout
        #pragma unroll
        for (int h = 0; h < 2; ++h)
            #pragma unroll
            for (int nn = 0; nn < 4; ++nn)
                #pragma unroll
                for (int r = 0; r < 4; ++r) {
                    float p = __expf(sc[h][nn][r]);
                    psum[h][r] += p;
                    Ps[w][h * 16 + (quad << 2) + r][nn * 16 + m16] = f2bf(p);
                }

        // O += P V (per-wave LDS round-trip, in-order within wave)
        bf16x8 pf[2][2];
        #pragma unroll
        for (int h = 0; h < 2; ++h)
            #pragma unroll
            for (int hf = 0; hf < 2; ++hf)
                pf[h][hf] = *(const bf16x8*)&Ps[w][h * 16 + m16][hf * 32 + quad * 8];
        #pragma unroll
        for (int h = 0; h < 2; ++h)
            #pragma unroll
            for (int nn = 0; nn < 4; ++nn) {
                acc[h][nn] = __builtin_amdgcn_mfma_f32_16x16x32_bf16(pf[h][0], vf[nn][0], acc[h][nn], 0, 0, 0);
                acc[h][nn] = __builtin_amdgcn_mfma_f32_16x16x32_bf16(pf[h][1], vf[nn][1], acc[h][nn], 0, 0, 0);
            }
    }

    // cross-wave combine (linear: no-max softmax partials just add)
    if (w == 0) {
        #pragma unroll
        for (int h = 0; h < 2; ++h)
            #pragma unroll
            for (int nn = 0; nn < 4; ++nn)
                #pragma unroll
                for (int r = 0; r < 4; ++r)
                    comb[l][(h * 4 + nn) * 4 + r] = acc[h][nn][r];
        #pragma unroll
        for (int h = 0; h < 2; ++h)
            #pragma unroll
            for (int r = 0; r < 4; ++r)
                comb[l][32 + h * 4 + r] = psum[h][r];
    }
    __syncthreads();
    if (w == 1) {
        #pragma unroll
        for (int h = 0; h < 2; ++h)
            #pragma unroll
            for (int nn = 0; nn < 4; ++nn)
                #pragma unroll
                for (int r = 0; r < 4; ++r)
                    acc[h][nn][r] += comb[l][(h * 4 + nn) * 4 + r];
        float inv[2][4];
        #pragma unroll
        for (int h = 0; h < 2; ++h)
            #pragma unroll
            for (int r = 0; r < 4; ++r) {
                float ps = psum[h][r] + comb[l][32 + h * 4 + r];
                ps += __shfl_xor(ps, 1);
                ps += __shfl_xor(ps, 2);
                ps += __shfl_xor(ps, 4);
                ps += __shfl_xor(ps, 8);
                inv[h][r] = 1.f / ps;
            }
        unsigned short* Og = qo + (bh * S_ + q0) * DK_;
        #pragma unroll
        for (int h = 0; h < 2; ++h)
            #pragma unroll
            for (int r = 0; r < 4; ++r)
                #pragma unroll
                for (int nn = 0; nn < 4; ++nn)
                    Og[(h * 16 + (quad << 2) + r) * DK_ + nn * 16 + m16] =
                        f2bf(acc[h][nn][r] * inv[h][r]);
    }
}

// ---------------------------------------------------------------------------
extern "C" void kernel_launch(void* const* d_in, const int* in_sizes, int n_in,
                              void* d_out, int out_size, void* d_ws, size_t ws_size,
                              hipStream_t stream) {
    const float* x  = (const float*)d_in[0];
    const float* pk = (const float*)d_in[1];
    const float* pv = (const float*)d_in[2];
    const float* Wq = (const float*)d_in[3];
    const float* bq = (const float*)d_in[4];
    const float* Wk = (const float*)d_in[5];
    const float* bk = (const float*)d_in[6];
    const float* Wv = (const float*)d_in[7];
    const float* bv = (const float*)d_in[8];
    const float* Wo = (const float*)d_in[9];
    const float* bo = (const float*)d_in[10];

    float* out     = (float*)d_out;            // (8,512,512)
    float* kout    = out + 2097152;            // (8,8,1024,64)
    float* vout    = kout + 4194304;           // (8,8,1024,64)
    float* off_out = vout + 4194304;           // scalar 1024.0

    // workspace: 20 MB
    unsigned short* Qb = (unsigned short*)d_ws; // [0,4MB)  Q bf16 (B,H,S,DK); O in place after attn
    unsigned short* Kp = Qb + 2097152;          // [4,12MB) packed K fragments bf16
    unsigned short* Vp = Kp + 4194304;          // [12,20MB) packed V fragments bf16

    // 1) cache shift + offset
    prep_kernel<<<2048, 256, 0, stream>>>((const float4*)pk, (const float4*)pv,
                                          (float4*)kout, (float4*)vout, off_out);
    // 2) QKV projections (fp32 in, convert in-kernel)
    qkv_mfma_kernel<<<dim3(8, 32, 3), 256, 0, stream>>>(x, Wq, bq, Wk, bk, Wv, bv,
                                                        Qb, kout, vout);
    // 3) pack K/V into fragment order
    pack_kernel<<<dim3(16, 64), 256, 0, stream>>>(kout, vout, Kp, Vp);
    // 4) attention (barrier-free tile loop, split-K waves); O replaces Q
    attn_kernel<<<dim3(64, 16), 128, 0, stream>>>(Qb, Kp, Vp);
    // 5) output projection
    out_mfma_kernel<<<dim3(8, 64), 256, 0, stream>>>(Qb, Wo, bo, out);
}

// Round 6
// 164.996 us; speedup vs baseline: 1.3693x; 1.0091x over previous
//
#include <hip/hip_runtime.h>
#include <math.h>

#define B_  8
#define S_  512
#define D_  512
#define H_  8
#define DK_ 64
#define KL_ 1024

typedef __attribute__((ext_vector_type(8))) short bf16x8;
typedef __attribute__((ext_vector_type(4))) float f32x4;

__device__ __forceinline__ unsigned short f2bf(float f) {   // RNE
    unsigned u = __float_as_uint(f);
    u += 0x7FFF + ((u >> 16) & 1);
    return (unsigned short)(u >> 16);
}
// async global->LDS, 16 B per lane; LDS dest = wave-uniform base + lane*16
__device__ __forceinline__ void gld16(const void* g, void* l) {
    __builtin_amdgcn_global_load_lds(
        (const __attribute__((address_space(1))) unsigned int*)g,
        (__attribute__((address_space(3))) unsigned int*)l, 16, 0, 0);
}

// ---------------------------------------------------------------------------
// prep (grid 2048):
//  blk 0..1023    : x fp32 -> bf16 (8 elems/thread)
//  blk 1024..1535 : Wq/Wk/Wv/Wo fp32 -> bf16 (128 blocks each)
//  blk 1536..2047 : copy prev rows 512..1023 -> kout/vout fp32 rows 0..511
//                   AND pack them into Kp/Vp bf16 fragment tiles kt 0..7
// ---------------------------------------------------------------------------
__global__ __launch_bounds__(256)
void prep_kernel(const float* __restrict__ x,
                 const float* __restrict__ Wq, const float* __restrict__ Wk,
                 const float* __restrict__ Wv, const float* __restrict__ Wo,
                 const float* __restrict__ pk, const float* __restrict__ pv,
                 unsigned short* __restrict__ xb,
                 unsigned short* __restrict__ Wqb, unsigned short* __restrict__ Wkb,
                 unsigned short* __restrict__ Wvb, unsigned short* __restrict__ Wob,
                 float* __restrict__ kout, float* __restrict__ vout,
                 unsigned short* __restrict__ Kp, unsigned short* __restrict__ Vp,
                 float* __restrict__ off_out) {
    const int blk = blockIdx.x, t = threadIdx.x;
    if (blk == 0 && t == 0) off_out[0] = 1024.0f;

    if (blk < 1536) {
        const float* src; unsigned short* dst; int off;
        if (blk < 1024) {
            src = x; dst = xb; off = blk * 256 + t;                 // [0, 262144)
        } else {
            int widx = blk - 1024;                                  // 0..511
            int grp = widx >> 7, wb = widx & 127;
            const float* ws_[4]        = {Wq, Wk, Wv, Wo};
            unsigned short* wd_[4]     = {Wqb, Wkb, Wvb, Wob};
            src = ws_[grp]; dst = wd_[grp]; off = wb * 256 + t;     // [0, 32768)
        }
        float4 v0 = ((const float4*)src)[off * 2];
        float4 v1 = ((const float4*)src)[off * 2 + 1];
        unsigned short tmp[8] = {f2bf(v0.x), f2bf(v0.y), f2bf(v0.z), f2bf(v0.w),
                                 f2bf(v1.x), f2bf(v1.y), f2bf(v1.z), f2bf(v1.w)};
        *(uint4*)&dst[off * 8] = *(uint4*)tmp;
        return;
    }

    // ---- copy + pack prev ----
    __shared__ float Kl[64][68];
    __shared__ float Vl[64][68];
    const int pb = blk - 1536;                  // 0..511
    const int kt = pb & 7, bh = pb >> 3;
    const float* Kg = pk + (bh * KL_ + 512 + kt * 64) * DK_;
    const float* Vg = pv + (bh * KL_ + 512 + kt * 64) * DK_;
    float* Ko = kout + (bh * KL_ + kt * 64) * DK_;
    float* Vo = vout + (bh * KL_ + kt * 64) * DK_;
    #pragma unroll
    for (int it = 0; it < 4; ++it) {
        int idx = t + it * 256;                 // 1024 float4 slots
        int row = idx >> 4, c4 = idx & 15;
        float4 kv = *(const float4*)&Kg[row * 64 + c4 * 4];
        float4 vv = *(const float4*)&Vg[row * 64 + c4 * 4];
        *(float4*)&Ko[row * 64 + c4 * 4] = kv;
        *(float4*)&Vo[row * 64 + c4 * 4] = vv;
        *(float4*)&Kl[row][c4 * 4] = kv;
        *(float4*)&Vl[row][c4 * 4] = vv;
    }
    __syncthreads();
    unsigned short* Kpb = Kp + (bh * 16 + kt) * 4096;
    unsigned short* Vpb = Vp + (bh * 16 + kt) * 4096;
    #pragma unroll
    for (int s = 0; s < 2; ++s) {
        int slot = t + s * 256;                 // 0..511
        int c = slot >> 6, l = slot & 63;
        int nn = c >> 1, hf = c & 1;
        {   // K chunk: K[key=nn*16+(l&15)][d=hf*32+(l>>4)*8 + j]
            int row = nn * 16 + (l & 15), col = hf * 32 + (l >> 4) * 8;
            unsigned short tmp[8];
            #pragma unroll
            for (int j = 0; j < 8; ++j) tmp[j] = f2bf(Kl[row][col + j]);
            *(uint4*)&Kpb[c * 512 + l * 8] = *(uint4*)tmp;
        }
        {   // V chunk: V[key=hf*32+(l>>4)*8+j][d=nn*16+(l&15)]
            int row0 = hf * 32 + (l >> 4) * 8, col = nn * 16 + (l & 15);
            unsigned short tmp[8];
            #pragma unroll
            for (int j = 0; j < 8; ++j) tmp[j] = f2bf(Vl[row0 + j][col]);
            *(uint4*)&Vpb[c * 512 + l * 8] = *(uint4*)tmp;
        }
    }
}

// ---------------------------------------------------------------------------
// m97-style MFMA GEMM: C(4096x512) = A_bf16 @ W_bf16^T + bias.
// BM x 64 tile, 4 waves 2x2 (wave tile (BM/2)x32), BK=32, gld16 staging.
// MODE 1: C bf16 *0.125 scatter (B,H,S,DK)                      [Q]
// MODE 2: C fp32 scatter (B,H,KL,DK) rows 512+, pack Kp tiles   [K]
// MODE 4: same as 2 but pack Vp tiles (d-major transpose)       [V]
// MODE 3: C fp32 row-major                                      [out]
// ---------------------------------------------------------------------------
template<int MODE, int BM>
__device__ __forceinline__
void mfma_gemm_body(const unsigned short* __restrict__ A,
                    const unsigned short* __restrict__ Wb,
                    const float* __restrict__ bias,
                    float* __restrict__ C32, unsigned short* __restrict__ C16,
                    unsigned short* __restrict__ Pk) {
    constexpr int MM = BM / 32;                 // m-tiles per wave
    __shared__ unsigned short As[BM * 32];
    __shared__ unsigned short Bs[64 * 32];
    const int t = threadIdx.x, l = t & 63, w = t >> 6;
    const int m16 = l & 15, quad = l >> 4;
    const int wm = w >> 1, wn = w & 1;
    const int bn = blockIdx.x, bm = blockIdx.y;
    const int lr = l >> 2, lc = (l & 3) * 8;    // 4 lanes per 64B row-piece

    f32x4 acc[MM][2] = {};
    const unsigned short* Ag = A + (bm * BM) * 512;
    const unsigned short* Wg = Wb + (bn * 64) * 512;

    for (int k0 = 0; k0 < 512; k0 += 32) {
        __syncthreads();
        #pragma unroll
        for (int q = 0; q < BM / 64; ++q) {     // A: BM/16 chunks of 16 rows
            int chunk = w * (BM / 64) + q;
            gld16(Ag + (chunk * 16 + lr) * 512 + k0 + lc, &As[chunk * 512 + l * 8]);
        }
        gld16(Wg + (w * 16 + lr) * 512 + k0 + lc, &Bs[w * 512 + l * 8]);
        __syncthreads();

        bf16x8 af[MM], bfr[2];
        #pragma unroll
        for (int mm = 0; mm < MM; ++mm)
            af[mm] = *(const bf16x8*)&As[(wm * (BM / 2) + mm * 16 + m16) * 32 + quad * 8];
        #pragma unroll
        for (int nn = 0; nn < 2; ++nn)
            bfr[nn] = *(const bf16x8*)&Bs[(wn * 32 + nn * 16 + m16) * 32 + quad * 8];
        #pragma unroll
        for (int mm = 0; mm < MM; ++mm)
            #pragma unroll
            for (int nn = 0; nn < 2; ++nn)
                acc[mm][nn] = __builtin_amdgcn_mfma_f32_16x16x32_bf16(
                    af[mm], bfr[nn], acc[mm][nn], 0, 0, 0);
    }

    // ---- epilogue: C/D row = quad*4+r, col = m16 [m89/m91] ----
    if constexpr (MODE == 2 || MODE == 4) {
        __shared__ __attribute__((aligned(16))) unsigned short Ts[9216];
        #pragma unroll
        for (int mm = 0; mm < MM; ++mm)
            #pragma unroll
            for (int nn = 0; nn < 2; ++nn) {
                int n = bn * 64 + wn * 32 + nn * 16 + m16;
                float bv_ = bias[n];
                int d = n & 63;
                #pragma unroll
                for (int r = 0; r < 4; ++r) {
                    int ml = wm * (BM / 2) + mm * 16 + quad * 4 + r;
                    int m = bm * BM + ml;
                    float val = acc[mm][nn][r] + bv_;
                    int b = m >> 9, s = m & 511, h = n >> 6;
                    C32[((b * H_ + h) * KL_ + 512 + s) * DK_ + d] = val;
                    if (MODE == 2) Ts[ml * 72 + d]  = f2bf(val);   // key-major
                    else           Ts[d * 136 + ml] = f2bf(val);   // d-major
                }
            }
        __syncthreads();
        // two complete packed tiles per block (BM=128 rows = 2 key-tiles)
        const int bh = (bm >> 2) * H_ + bn;
        const int kt0 = 8 + (bm & 3) * 2;
        #pragma unroll
        for (int T = 0; T < 2; ++T)
            #pragma unroll
            for (int cp = 0; cp < 2; ++cp) {
                int c = w * 2 + cp, nn = c >> 1, hf = c & 1;
                uint4 frag;
                if (MODE == 2)
                    frag = *(const uint4*)&Ts[(T * 64 + nn * 16 + (l & 15)) * 72
                                              + hf * 32 + (l >> 4) * 8];
                else
                    frag = *(const uint4*)&Ts[(nn * 16 + (l & 15)) * 136
                                              + T * 64 + hf * 32 + (l >> 4) * 8];
                *(uint4*)&Pk[((bh * 16 + kt0 + T) * 4096) + c * 512 + l * 8] = frag;
            }
    } else {
        #pragma unroll
        for (int mm = 0; mm < MM; ++mm)
            #pragma unroll
            for (int nn = 0; nn < 2; ++nn) {
                int n = bn * 64 + wn * 32 + nn * 16 + m16;
                float bv_ = bias[n];
                #pragma unroll
                for (int r = 0; r < 4; ++r) {
                    int m = bm * BM + wm * (BM / 2) + mm * 16 + quad * 4 + r;
                    float val = acc[mm][nn][r] + bv_;
                    if (MODE == 3) {
                        C32[m * 512 + n] = val;
                    } else {                    // MODE 1: Q bf16 scatter, pre-scaled
                        int b = m >> 9, s = m & 511;
                        int h = n >> 6, d = n & 63;
                        C16[((b * H_ + h) * S_ + s) * DK_ + d] = f2bf(val * 0.125f);
                    }
                }
            }
    }
}

__global__ __launch_bounds__(256)
void qkv_mfma_kernel(const unsigned short* __restrict__ xb,
                     const unsigned short* __restrict__ Wqb, const float* __restrict__ bq,
                     const unsigned short* __restrict__ Wkb, const float* __restrict__ bk,
                     const unsigned short* __restrict__ Wvb, const float* __restrict__ bv,
                     unsigned short* __restrict__ Qb, float* __restrict__ kout,
                     float* __restrict__ vout,
                     unsigned short* __restrict__ Kp, unsigned short* __restrict__ Vp) {
    if (blockIdx.z == 0)      mfma_gemm_body<1, 128>(xb, Wqb, bq, nullptr, Qb, nullptr);
    else if (blockIdx.z == 1) mfma_gemm_body<2, 128>(xb, Wkb, bk, kout, nullptr, Kp);
    else                      mfma_gemm_body<4, 128>(xb, Wvb, bv, vout, nullptr, Vp);
}

__global__ __launch_bounds__(256)
void out_mfma_kernel(const unsigned short* __restrict__ Ob, const unsigned short* __restrict__ Wob,
                     const float* __restrict__ bo, float* __restrict__ C) {
    mfma_gemm_body<3, 64>(Ob, Wob, bo, C, nullptr, nullptr);
}

// ---------------------------------------------------------------------------
// Packed-fragment flash attention (round-5 structure), no-max softmax,
// split-K across 2 waves, ONE barrier for the combine. O -> row-major
// (B,S,D) bf16 so the out-GEMM gets a contiguous A.
// ---------------------------------------------------------------------------
__global__ __launch_bounds__(128)
void attn_kernel(const unsigned short* __restrict__ Qb,
                 const unsigned short* __restrict__ Kp,
                 const unsigned short* __restrict__ Vp,
                 unsigned short* __restrict__ Ob) {
    const int bh = blockIdx.x, qg = blockIdx.y;
    const int t = threadIdx.x, l = t & 63, w = t >> 6;
    const int m16 = l & 15, quad = l >> 4;
    const int q0 = qg * 32;

    __shared__ __attribute__((aligned(16))) unsigned short Ps[2][32][72];
    __shared__ float comb[64][40];

    bf16x8 qf[2][2];
    #pragma unroll
    for (int qh = 0; qh < 2; ++qh)
        #pragma unroll
        for (int p = 0; p < 2; ++p)
            qf[qh][p] = *(const bf16x8*)(Qb + (bh * S_ + q0 + qh * 16 + m16) * DK_
                                            + p * 32 + quad * 8);

    f32x4 acc[2][4] = {};
    float psum[2][4] = {};

    const int ktmax = (543 + q0) >> 6;
    const unsigned short* Kpb = Kp + (bh * 16) * 4096;
    const unsigned short* Vpb = Vp + (bh * 16) * 4096;

    for (int kt = w; kt <= ktmax; kt += 2) {
        const unsigned short* kb = Kpb + kt * 4096;
        const unsigned short* vb = Vpb + kt * 4096;
        bf16x8 kf[4][2], vf[4][2];
        #pragma unroll
        for (int nn = 0; nn < 4; ++nn)
            #pragma unroll
            for (int hf = 0; hf < 2; ++hf) {
                kf[nn][hf] = *(const bf16x8*)(kb + ((nn * 2 + hf) * 64 + l) * 8);
                vf[nn][hf] = *(const bf16x8*)(vb + ((nn * 2 + hf) * 64 + l) * 8);
            }

        f32x4 sc[2][4];
        #pragma unroll
        for (int qh = 0; qh < 2; ++qh)
            #pragma unroll
            for (int nn = 0; nn < 4; ++nn) {
                sc[qh][nn][0] = sc[qh][nn][1] = sc[qh][nn][2] = sc[qh][nn][3] = 0.f;
                sc[qh][nn] = __builtin_amdgcn_mfma_f32_16x16x32_bf16(qf[qh][0], kf[nn][0], sc[qh][nn], 0, 0, 0);
                sc[qh][nn] = __builtin_amdgcn_mfma_f32_16x16x32_bf16(qf[qh][1], kf[nn][1], sc[qh][nn], 0, 0, 0);
            }

        if (kt == ktmax) {                      // causal mask, boundary tile only
            #pragma unroll
            for (int qh = 0; qh < 2; ++qh)
                #pragma unroll
                for (int nn = 0; nn < 4; ++nn) {
                    int key = kt * 64 + nn * 16 + m16;
                    #pragma unroll
                    for (int r = 0; r < 4; ++r)
                        if (key > 512 + q0 + qh * 16 + (quad << 2) + r)
                            sc[qh][nn][r] = -INFINITY;
                }
        }

        #pragma unroll
        for (int qh = 0; qh < 2; ++qh)
            #pragma unroll
            for (int nn = 0; nn < 4; ++nn)
                #pragma unroll
                for (int r = 0; r < 4; ++r) {
                    float p = __expf(sc[qh][nn][r]);
                    psum[qh][r] += p;
                    Ps[w][qh * 16 + (quad << 2) + r][nn * 16 + m16] = f2bf(p);
                }

        bf16x8 pf[2][2];
        #pragma unroll
        for (int qh = 0; qh < 2; ++qh)
            #pragma unroll
            for (int hf = 0; hf < 2; ++hf)
                pf[qh][hf] = *(const bf16x8*)&Ps[w][qh * 16 + m16][hf * 32 + quad * 8];
        #pragma unroll
        for (int qh = 0; qh < 2; ++qh)
            #pragma unroll
            for (int nn = 0; nn < 4; ++nn) {
                acc[qh][nn] = __builtin_amdgcn_mfma_f32_16x16x32_bf16(pf[qh][0], vf[nn][0], acc[qh][nn], 0, 0, 0);
                acc[qh][nn] = __builtin_amdgcn_mfma_f32_16x16x32_bf16(pf[qh][1], vf[nn][1], acc[qh][nn], 0, 0, 0);
            }
    }

    if (w == 0) {
        #pragma unroll
        for (int qh = 0; qh < 2; ++qh)
            #pragma unroll
            for (int nn = 0; nn < 4; ++nn)
                #pragma unroll
                for (int r = 0; r < 4; ++r)
                    comb[l][(qh * 4 + nn) * 4 + r] = acc[qh][nn][r];
        #pragma unroll
        for (int qh = 0; qh < 2; ++qh)
            #pragma unroll
            for (int r = 0; r < 4; ++r)
                comb[l][32 + qh * 4 + r] = psum[qh][r];
    }
    __syncthreads();
    if (w == 1) {
        #pragma unroll
        for (int qh = 0; qh < 2; ++qh)
            #pragma unroll
            for (int nn = 0; nn < 4; ++nn)
                #pragma unroll
                for (int r = 0; r < 4; ++r)
                    acc[qh][nn][r] += comb[l][(qh * 4 + nn) * 4 + r];
        float inv[2][4];
        #pragma unroll
        for (int qh = 0; qh < 2; ++qh)
            #pragma unroll
            for (int r = 0; r < 4; ++r) {
                float ps = psum[qh][r] + comb[l][32 + qh * 4 + r];
                ps += __shfl_xor(ps, 1);
                ps += __shfl_xor(ps, 2);
                ps += __shfl_xor(ps, 4);
                ps += __shfl_xor(ps, 8);
                inv[qh][r] = 1.f / ps;
            }
        // O row-major (B,S,D): row b*512 + q, col h*64 + d
        unsigned short* Og = Ob + ((bh >> 3) * S_ + q0) * D_ + (bh & 7) * DK_;
        #pragma unroll
        for (int qh = 0; qh < 2; ++qh)
            #pragma unroll
            for (int r = 0; r < 4; ++r)
                #pragma unroll
                for (int nn = 0; nn < 4; ++nn)
                    Og[(qh * 16 + (quad << 2) + r) * D_ + nn * 16 + m16] =
                        f2bf(acc[qh][nn][r] * inv[qh][r]);
    }
}

// ---------------------------------------------------------------------------
extern "C" void kernel_launch(void* const* d_in, const int* in_sizes, int n_in,
                              void* d_out, int out_size, void* d_ws, size_t ws_size,
                              hipStream_t stream) {
    const float* x  = (const float*)d_in[0];
    const float* pk = (const float*)d_in[1];
    const float* pv = (const float*)d_in[2];
    const float* Wq = (const float*)d_in[3];
    const float* bq = (const float*)d_in[4];
    const float* Wk = (const float*)d_in[5];
    const float* bk = (const float*)d_in[6];
    const float* Wv = (const float*)d_in[7];
    const float* bv = (const float*)d_in[8];
    const float* Wo = (const float*)d_in[9];
    const float* bo = (const float*)d_in[10];

    float* out     = (float*)d_out;             // (8,512,512)
    float* kout    = out + 2097152;             // (8,8,1024,64)
    float* vout    = kout + 4194304;            // (8,8,1024,64)
    float* off_out = vout + 4194304;            // scalar 1024.0

    // workspace layout (bf16 elements), 26 MB total:
    unsigned short* xb  = (unsigned short*)d_ws;  // [0,4MB)  x bf16; Ob aliases after qkv
    unsigned short* Wqb = xb + 2097152;           // [4,4.5MB)
    unsigned short* Wkb = Wqb + 262144;           // [4.5,5MB)
    unsigned short* Wvb = Wkb + 262144;           // [5,5.5MB)
    unsigned short* Wob = Wvb + 262144;           // [5.5,6MB)
    unsigned short* Qb  = Wob + 262144;           // [6,10MB)  Q bf16 (B,H,S,DK), pre-scaled
    unsigned short* Kp  = Qb + 2097152;           // [10,18MB) packed K fragments
    unsigned short* Vp  = Kp + 4194304;           // [18,26MB) packed V fragments
    unsigned short* Ob  = xb;                     // O bf16 (B,S,D) row-major (xb dead)

    // 1) converts + cache shift + prev pack + offset
    prep_kernel<<<2048, 256, 0, stream>>>(x, Wq, Wk, Wv, Wo, pk, pv,
                                          xb, Wqb, Wkb, Wvb, Wob,
                                          kout, vout, Kp, Vp, off_out);
    // 2) QKV projections; K/V epilogues emit packed tiles kt 8..15
    qkv_mfma_kernel<<<dim3(8, 32, 3), 256, 0, stream>>>(xb, Wqb, bq, Wkb, bk, Wvb, bv,
                                                        Qb, kout, vout, Kp, Vp);
    // 3) attention; O -> row-major bf16
    attn_kernel<<<dim3(64, 16), 128, 0, stream>>>(Qb, Kp, Vp, Ob);
    // 4) output projection (both operands bf16)
    out_mfma_kernel<<<dim3(8, 64), 256, 0, stream>>>(Ob, Wob, bo, out);
}